// Round 1
// baseline (193.930 us; speedup 1.0000x reference)
//
#include <hip/hip_runtime.h>
#include <hip/hip_bf16.h>

typedef unsigned short u16;
typedef unsigned int u32;
typedef __bf16 bf16x8 __attribute__((ext_vector_type(8)));
typedef float floatx4 __attribute__((ext_vector_type(4)));

#define MFMA16(a,b,c) __builtin_amdgcn_mfma_f32_16x16x32_bf16((a),(b),(c),0,0,0)

__device__ __forceinline__ u16 f2bf(float f){
  u32 u = __builtin_bit_cast(u32, f);
  u += 0x7FFFu + ((u >> 16) & 1u);
  return (u16)(u >> 16);
}
__device__ __forceinline__ float bf2f(u16 h){
  u32 u = ((u32)h) << 16;
  return __builtin_bit_cast(float, u);
}
__device__ __forceinline__ bf16x8 ldfrag(const u16* p){
  return *(const bf16x8*)p;
}

// ---------------- K0: combine weights (stack is [x, Ax, Ax] -> m0, m1+m2) ----
// WgT[n][k]: n in [0,128), k in [0,384). k<128: x-features; 128..255: A0x; 256..383: A1x
__global__ __launch_bounds__(256) void k0_prep(
    const float* __restrict__ W0, const float* __restrict__ b0,
    const float* __restrict__ W1, const float* __restrict__ b1,
    const float* __restrict__ Wc0, const float* __restrict__ bc0,
    const float* __restrict__ Wc1, const float* __restrict__ bc1,
    u16* __restrict__ WgT, u16* __restrict__ WcT,
    float* __restrict__ bias_g, float* __restrict__ bias_c){
  int id = blockIdx.x*256 + threadIdx.x;
  if (id < 128*384) {
    int n = id / 384, k = id % 384;
    float v;
    if (k < 128)       v = W0[(k*3+0)*128 + n] + W1[(k*3+0)*128 + n];
    else if (k < 256){ int f = k-128; v = W0[(f*3+1)*128+n] + W0[(f*3+2)*128+n]; }
    else             { int f = k-256; v = W1[(f*3+1)*128+n] + W1[(f*3+2)*128+n]; }
    WgT[(size_t)n*384 + k] = f2bf(v);
  } else {
    int id2 = id - 128*384;  // < 64*384
    int n = id2 / 384, k = id2 % 384;
    float v;
    if (k < 128)       v = Wc0[(k*3+0)*64 + n] + Wc1[(k*3+0)*64 + n];
    else if (k < 256){ int f = k-128; v = Wc0[(f*3+1)*64+n] + Wc0[(f*3+2)*64+n]; }
    else             { int f = k-256; v = Wc1[(f*3+1)*64+n] + Wc1[(f*3+2)*64+n]; }
    WcT[(size_t)n*384 + k] = f2bf(v);
  }
  if (blockIdx.x == 0) {
    if (threadIdx.x < 128) bias_g[threadIdx.x] = b0[threadIdx.x] + b1[threadIdx.x];
    if (threadIdx.x < 64)  bias_c[threadIdx.x] = bc0[threadIdx.x] + bc1[threadIdx.x];
  }
}

// ---------------- K1: adj pass: row/col sums + bf16 copy + transposed bf16 copy
__global__ __launch_bounds__(256) void k1_adj(const float* __restrict__ adj,
    u16* __restrict__ adjbf, u16* __restrict__ adjTbf,
    float* __restrict__ colsum, float* __restrict__ rowsum){
  __shared__ u16 lt[64][72];            // lt[j_local][i_local]
  int b = blockIdx.z;
  int i0 = blockIdx.y << 6, j0 = blockIdx.x << 6;
  int t = threadIdx.x;
  int r = t >> 2, cq = t & 3;
  size_t base = ((size_t)b << 20);
  const float4* s4 = (const float4*)(adj + base + (size_t)(i0 + r)*1024 + j0 + (cq<<4));
  float v[16];
  #pragma unroll
  for (int q = 0; q < 4; q++) {
    float4 f = s4[q];
    v[4*q]=f.x; v[4*q+1]=f.y; v[4*q+2]=f.z; v[4*q+3]=f.w;
  }
  u32 u8[8];
  #pragma unroll
  for (int q = 0; q < 8; q++)
    u8[q] = (u32)f2bf(v[2*q]) | ((u32)f2bf(v[2*q+1]) << 16);
  // row-major bf16 copy
  uint4* d = (uint4*)(adjbf + base + (size_t)(i0 + r)*1024 + j0 + (cq<<4));
  d[0] = make_uint4(u8[0],u8[1],u8[2],u8[3]);
  d[1] = make_uint4(u8[4],u8[5],u8[6],u8[7]);
  // row sums (f32, used for d1 = rowsum+1)
  float rs = 0.f;
  #pragma unroll
  for (int q = 0; q < 16; q++) rs += v[q];
  rs += __shfl_down(rs, 1, 64);
  rs += __shfl_down(rs, 2, 64);
  if (cq == 0) atomicAdd(&rowsum[b*1024 + i0 + r], rs);
  // transposed store into LDS
  #pragma unroll
  for (int q = 0; q < 16; q++)
    lt[(cq<<4) + q][r] = (u16)(u8[q>>1] >> ((q&1)*16));
  __syncthreads();
  // phase 2: write adjT rows, accumulate col sums
  uint4 q0 = *(const uint4*)&lt[r][(cq<<4)];
  uint4 q1 = *(const uint4*)&lt[r][(cq<<4) + 8];
  uint4* dT = (uint4*)(adjTbf + base + (size_t)(j0 + r)*1024 + i0 + (cq<<4));
  dT[0] = q0; dT[1] = q1;
  u32 w8[8] = {q0.x,q0.y,q0.z,q0.w,q1.x,q1.y,q1.z,q1.w};
  float cs = 0.f;
  #pragma unroll
  for (int q = 0; q < 8; q++)
    cs += bf2f((u16)(w8[q] & 0xFFFFu)) + bf2f((u16)(w8[q] >> 16));
  cs += __shfl_down(cs, 1, 64);
  cs += __shfl_down(cs, 2, 64);
  if (cq == 0) atomicAdd(&colsum[b*1024 + j0 + r], cs);
}

// ---------------- K1c: finalize dinv in place ----
__global__ __launch_bounds__(256) void k1c_dinv(float* __restrict__ colsum,
                                                float* __restrict__ rowsum){
  int i = blockIdx.x*256 + threadIdx.x;   // 16384
  colsum[i] = 1.0f / (colsum[i] + 1.0f);  // becomes d0inv
  rowsum[i] = 1.0f / (rowsum[i] + 1.0f);  // becomes d1inv
}

// ---------------- K1b: stage X = [inp|hx]: XC rows, Xt feature-major, XC2 inp cols
__global__ __launch_bounds__(256) void k1b_x(const float* __restrict__ inp,
    const float* __restrict__ hx, u16* __restrict__ XC,
    u16* __restrict__ Xt, u16* __restrict__ XC2){
  int t = threadIdx.x;
  int row = blockIdx.x*64 + (t>>2);
  int fq = t & 3;
  int b = row >> 10, n = row & 1023;
  const float4* ip = (const float4*)(inp + (size_t)row*64 + fq*16);
  const float4* hp = (const float4*)(hx  + (size_t)row*64 + fq*16);
  float iv[16], hv[16];
  #pragma unroll
  for (int q=0;q<4;q++){
    float4 a = ip[q]; iv[4*q]=a.x; iv[4*q+1]=a.y; iv[4*q+2]=a.z; iv[4*q+3]=a.w;
    float4 c = hp[q]; hv[4*q]=c.x; hv[4*q+1]=c.y; hv[4*q+2]=c.z; hv[4*q+3]=c.w;
  }
  u16 ib[16], hb[16];
  #pragma unroll
  for (int q=0;q<16;q++){ ib[q]=f2bf(iv[q]); hb[q]=f2bf(hv[q]); }
  u32 pi[8], ph[8];
  #pragma unroll
  for (int q=0;q<8;q++){
    pi[q] = (u32)ib[2*q] | ((u32)ib[2*q+1]<<16);
    ph[q] = (u32)hb[2*q] | ((u32)hb[2*q+1]<<16);
  }
  size_t rbase = (size_t)row*384;
  *(uint4*)(XC + rbase + fq*16)          = make_uint4(pi[0],pi[1],pi[2],pi[3]);
  *(uint4*)(XC + rbase + fq*16 + 8)      = make_uint4(pi[4],pi[5],pi[6],pi[7]);
  *(uint4*)(XC + rbase + 64 + fq*16)     = make_uint4(ph[0],ph[1],ph[2],ph[3]);
  *(uint4*)(XC + rbase + 64 + fq*16 + 8) = make_uint4(ph[4],ph[5],ph[6],ph[7]);
  *(uint4*)(XC2 + rbase + fq*16)         = make_uint4(pi[0],pi[1],pi[2],pi[3]);
  *(uint4*)(XC2 + rbase + fq*16 + 8)     = make_uint4(pi[4],pi[5],pi[6],pi[7]);
  u16* Xb = Xt + (size_t)b*131072;
  #pragma unroll
  for (int q=0;q<16;q++){
    Xb[(size_t)(fq*16+q)*1024 + n]      = ib[q];
    Xb[(size_t)(64+fq*16+q)*1024 + n]   = hb[q];
  }
}

// ---------------- K2: Y0/Y1 = dinv * ((adj(+T) @ X) + X), write into XC cols + XC2 inp-diffusion
__global__ __launch_bounds__(256) void k2_y(const u16* __restrict__ adjbf,
    const u16* __restrict__ adjTbf, const u16* __restrict__ Xt,
    const float* __restrict__ inp, const float* __restrict__ hx,
    const float* __restrict__ d0inv, const float* __restrict__ d1inv,
    u16* __restrict__ XC, u16* __restrict__ XC2){
  int bid = blockIdx.x;               // 512 blocks
  bool T = bid >= 256;
  int id = T ? bid - 256 : bid;
  int b = id >> 4, itile = id & 15;   // 16 tiles of 64 rows
  const u16* A = (T ? adjTbf : adjbf) + ((size_t)b << 20);
  const float* dinv = (T ? d1inv : d0inv) + b*1024;
  const u16* Xb = Xt + (size_t)b*131072;
  int w = threadIdx.x >> 6, l = threadIdx.x & 63, lr = l & 15, lg = l >> 4;
  int i0 = itile*64 + w*16;           // this wave's 16 output rows
  floatx4 acc[8] = {};
  for (int kk = 0; kk < 1024; kk += 32) {
    int ko = kk + lg*8;
    bf16x8 a = ldfrag(A + (size_t)(i0 + lr)*1024 + ko);
    bf16x8 bb[8];
    #pragma unroll
    for (int nf = 0; nf < 8; nf++)
      bb[nf] = ldfrag(Xb + (size_t)(nf*16 + lr)*1024 + ko);
    #pragma unroll
    for (int nf = 0; nf < 8; nf++)
      acc[nf] = MFMA16(a, bb[nf], acc[nf]);
  }
  int outcol = T ? 256 : 128;
  #pragma unroll
  for (int nf = 0; nf < 8; nf++) {
    #pragma unroll
    for (int rr = 0; rr < 4; rr++) {
      int row = i0 + lg*4 + rr;       // node within batch
      int col = nf*16 + lr;           // feature 0..127
      float xv = (col < 64) ? inp[(size_t)(b*1024+row)*64 + col]
                            : hx [(size_t)(b*1024+row)*64 + (col-64)];
      float v2 = (acc[nf][rr] + xv) * dinv[row];
      u16 bv = f2bf(v2);
      size_t grow = (size_t)(b*1024 + row)*384;
      XC[grow + outcol + col] = bv;
      if (col < 64) XC2[grow + outcol + col] = bv;   // A@inp half for candidate
    }
  }
}

// ---------------- K3: gates GEMM + sigmoid; emit u and S=r*hx (row-major + feature-major)
__global__ __launch_bounds__(256) void k3_gates(const u16* __restrict__ XC,
    const u16* __restrict__ WgT, const float* __restrict__ bias_g,
    const float* __restrict__ hx, u16* __restrict__ XC2,
    u16* __restrict__ St, float* __restrict__ uBuf){
  int w = threadIdx.x >> 6, l = threadIdx.x & 63, lr = l & 15, lg = l >> 4;
  int r0 = blockIdx.x*64 + w*16;
  floatx4 acc[8] = {};
  for (int kk = 0; kk < 384; kk += 32) {
    int ko = kk + lg*8;
    bf16x8 a = ldfrag(XC + (size_t)(r0 + lr)*384 + ko);
    #pragma unroll
    for (int nf = 0; nf < 8; nf++)
      acc[nf] = MFMA16(a, ldfrag(WgT + (size_t)(nf*16+lr)*384 + ko), acc[nf]);
  }
  #pragma unroll
  for (int nf = 0; nf < 8; nf++) {
    #pragma unroll
    for (int rr = 0; rr < 4; rr++) {
      int row = r0 + lg*4 + rr;
      int col = nf*16 + lr;
      float pre = acc[nf][rr] + bias_g[col];
      float s = 1.0f / (1.0f + __expf(-pre));
      if (col < 64) {            // r gate
        float sh = s * hx[(size_t)row*64 + col];
        u16 bv = f2bf(sh);
        XC2[(size_t)row*384 + 64 + col] = bv;
        int gb = row >> 10, n = row & 1023;
        St[(size_t)gb*65536 + (size_t)col*1024 + n] = bv;
      } else {                   // u gate
        uBuf[(size_t)row*64 + (col-64)] = s;
      }
    }
  }
}

// ---------------- K4: Z0/Z1 = dinv * ((adj(+T) @ S) + S) into XC2 cols
__global__ __launch_bounds__(256) void k4_z(const u16* __restrict__ adjbf,
    const u16* __restrict__ adjTbf, const u16* __restrict__ St,
    const float* __restrict__ d0inv, const float* __restrict__ d1inv,
    u16* __restrict__ XC2){
  int bid = blockIdx.x;               // 512 blocks
  bool T = bid >= 256;
  int id = T ? bid - 256 : bid;
  int b = id >> 4, itile = id & 15;
  const u16* A = (T ? adjTbf : adjbf) + ((size_t)b << 20);
  const float* dinv = (T ? d1inv : d0inv) + b*1024;
  const u16* Sb = St + (size_t)b*65536;
  int w = threadIdx.x >> 6, l = threadIdx.x & 63, lr = l & 15, lg = l >> 4;
  int i0 = itile*64 + w*16;
  floatx4 acc[4] = {};
  for (int kk = 0; kk < 1024; kk += 32) {
    int ko = kk + lg*8;
    bf16x8 a = ldfrag(A + (size_t)(i0 + lr)*1024 + ko);
    bf16x8 bb[4];
    #pragma unroll
    for (int nf = 0; nf < 4; nf++)
      bb[nf] = ldfrag(Sb + (size_t)(nf*16 + lr)*1024 + ko);
    #pragma unroll
    for (int nf = 0; nf < 4; nf++)
      acc[nf] = MFMA16(a, bb[nf], acc[nf]);
  }
  int zcol = T ? 320 : 192;
  #pragma unroll
  for (int nf = 0; nf < 4; nf++) {
    #pragma unroll
    for (int rr = 0; rr < 4; rr++) {
      int row = i0 + lg*4 + rr;
      int col = nf*16 + lr;
      size_t grow = (size_t)(b*1024 + row)*384;
      float sval = bf2f(XC2[grow + 64 + col]);
      float v2 = (acc[nf][rr] + sval) * dinv[row];
      XC2[grow + zcol + col] = f2bf(v2);
    }
  }
}

// ---------------- K5: candidate GEMM + tanh + GRU update -> out
__global__ __launch_bounds__(256) void k5_out(const u16* __restrict__ XC2,
    const u16* __restrict__ WcT, const float* __restrict__ bias_c,
    const float* __restrict__ uBuf, const float* __restrict__ hx,
    float* __restrict__ out){
  int w = threadIdx.x >> 6, l = threadIdx.x & 63, lr = l & 15, lg = l >> 4;
  int r0 = blockIdx.x*64 + w*16;
  floatx4 acc[4] = {};
  for (int kk = 0; kk < 384; kk += 32) {
    int ko = kk + lg*8;
    bf16x8 a = ldfrag(XC2 + (size_t)(r0 + lr)*384 + ko);
    #pragma unroll
    for (int nf = 0; nf < 4; nf++)
      acc[nf] = MFMA16(a, ldfrag(WcT + (size_t)(nf*16+lr)*384 + ko), acc[nf]);
  }
  #pragma unroll
  for (int nf = 0; nf < 4; nf++) {
    #pragma unroll
    for (int rr = 0; rr < 4; rr++) {
      int row = r0 + lg*4 + rr;
      int col = nf*16 + lr;
      float pre = acc[nf][rr] + bias_c[col];
      pre = fminf(fmaxf(pre, -15.f), 15.f);
      float e2 = __expf(2.0f*pre);
      float c = (e2 - 1.0f) / (e2 + 1.0f);
      float u = uBuf[(size_t)row*64 + col];
      float h = hx[(size_t)row*64 + col];
      out[(size_t)row*64 + col] = u*h + (1.0f - u)*c;
    }
  }
}

extern "C" void kernel_launch(void* const* d_in, const int* in_sizes, int n_in,
                              void* d_out, int out_size, void* d_ws, size_t ws_size,
                              hipStream_t stream) {
  (void)in_sizes; (void)n_in; (void)out_size; (void)ws_size;
  const float* inp = (const float*)d_in[0];
  const float* hx  = (const float*)d_in[1];
  const float* adj = (const float*)d_in[2];
  const float* W0  = (const float*)d_in[3];
  const float* b0  = (const float*)d_in[4];
  const float* W1  = (const float*)d_in[5];
  const float* b1  = (const float*)d_in[6];
  const float* Wc0 = (const float*)d_in[7];
  const float* bc0 = (const float*)d_in[8];
  const float* Wc1 = (const float*)d_in[9];
  const float* bc1 = (const float*)d_in[10];
  float* out = (float*)d_out;
  char* ws = (char*)d_ws;

  float* colsum = (float*)(ws + 0);            // -> d0inv after k1c
  float* rowsum = (float*)(ws + 65536);        // -> d1inv after k1c
  u16* adjbf  = (u16*)(ws + 131072);           // 33554432 B
  u16* adjTbf = (u16*)(ws + 33685504);         // 33554432 B
  u16* Xt     = (u16*)(ws + 67239936);         // 4194304 B
  u16* XC     = (u16*)(ws + 71434240);         // 12582912 B
  u16* XC2    = (u16*)(ws + 84017152);         // 12582912 B
  u16* St     = (u16*)(ws + 96600064);         // 2097152 B
  float* uBuf = (float*)(ws + 98697216);       // 4194304 B
  u16* WgT    = (u16*)(ws + 102891520);        // 98304 B
  u16* WcT    = (u16*)(ws + 102989824);        // 49152 B
  float* bias_g = (float*)(ws + 103038976);    // 512 B
  float* bias_c = (float*)(ws + 103039488);    // 256 B

  hipMemsetAsync(ws, 0, 131072, stream);
  hipLaunchKernelGGL(k0_prep, dim3(288), dim3(256), 0, stream,
                     W0, b0, W1, b1, Wc0, bc0, Wc1, bc1, WgT, WcT, bias_g, bias_c);
  hipLaunchKernelGGL(k1_adj, dim3(16,16,16), dim3(256), 0, stream,
                     adj, adjbf, adjTbf, colsum, rowsum);
  hipLaunchKernelGGL(k1c_dinv, dim3(64), dim3(256), 0, stream, colsum, rowsum);
  hipLaunchKernelGGL(k1b_x, dim3(256), dim3(256), 0, stream, inp, hx, XC, Xt, XC2);
  hipLaunchKernelGGL(k2_y, dim3(512), dim3(256), 0, stream,
                     adjbf, adjTbf, Xt, inp, hx, colsum, rowsum, XC, XC2);
  hipLaunchKernelGGL(k3_gates, dim3(256), dim3(256), 0, stream,
                     XC, WgT, bias_g, hx, XC2, St, uBuf);
  hipLaunchKernelGGL(k4_z, dim3(512), dim3(256), 0, stream,
                     adjbf, adjTbf, St, colsum, rowsum, XC2);
  hipLaunchKernelGGL(k5_out, dim3(256), dim3(256), 0, stream,
                     XC2, WcT, bias_c, uBuf, hx, out);
}

// Round 2
// 122.457 us; speedup vs baseline: 1.5837x; 1.5837x over previous
//
#include <hip/hip_runtime.h>
#include <hip/hip_bf16.h>

typedef unsigned short u16;
typedef unsigned int u32;
typedef __bf16 bf16x8 __attribute__((ext_vector_type(8)));
typedef float floatx4 __attribute__((ext_vector_type(4)));

#define MFMA16(a,b,c) __builtin_amdgcn_mfma_f32_16x16x32_bf16((a),(b),(c),0,0,0)
#define AS1 __attribute__((address_space(1)))
#define AS3 __attribute__((address_space(3)))

__device__ __forceinline__ void gl16(const void* g, void* l){
  // global -> LDS direct copy, 16B per lane; LDS dst = wave-uniform base + lane*16
  __builtin_amdgcn_global_load_lds((const AS1 void*)g, (AS3 void*)l, 16, 0, 0);
}

__device__ __forceinline__ u16 f2bf(float f){
  u32 u = __builtin_bit_cast(u32, f);
  u += 0x7FFFu + ((u >> 16) & 1u);
  return (u16)(u >> 16);
}
__device__ __forceinline__ float bf2f(u16 h){
  u32 u = ((u32)h) << 16;
  return __builtin_bit_cast(float, u);
}
__device__ __forceinline__ bf16x8 ldfrag(const u16* p){
  return *(const bf16x8*)p;
}

// ---------------- K0: combine weights (stack is [x, Ax, Ax] -> m0, m1+m2) ----
__global__ __launch_bounds__(256) void k0_prep(
    const float* __restrict__ W0, const float* __restrict__ b0,
    const float* __restrict__ W1, const float* __restrict__ b1,
    const float* __restrict__ Wc0, const float* __restrict__ bc0,
    const float* __restrict__ Wc1, const float* __restrict__ bc1,
    u16* __restrict__ WgT, u16* __restrict__ WcT,
    float* __restrict__ bias_g, float* __restrict__ bias_c){
  int id = blockIdx.x*256 + threadIdx.x;
  if (id < 128*384) {
    int n = id / 384, k = id % 384;
    float v;
    if (k < 128)       v = W0[(k*3+0)*128 + n] + W1[(k*3+0)*128 + n];
    else if (k < 256){ int f = k-128; v = W0[(f*3+1)*128+n] + W0[(f*3+2)*128+n]; }
    else             { int f = k-256; v = W1[(f*3+1)*128+n] + W1[(f*3+2)*128+n]; }
    WgT[(size_t)n*384 + k] = f2bf(v);
  } else {
    int id2 = id - 128*384;  // < 64*384
    int n = id2 / 384, k = id2 % 384;
    float v;
    if (k < 128)       v = Wc0[(k*3+0)*64 + n] + Wc1[(k*3+0)*64 + n];
    else if (k < 256){ int f = k-128; v = Wc0[(f*3+1)*64+n] + Wc0[(f*3+2)*64+n]; }
    else             { int f = k-256; v = Wc1[(f*3+1)*64+n] + Wc1[(f*3+2)*64+n]; }
    WcT[(size_t)n*384 + k] = f2bf(v);
  }
  if (blockIdx.x == 0) {
    if (threadIdx.x < 128) bias_g[threadIdx.x] = b0[threadIdx.x] + b1[threadIdx.x];
    if (threadIdx.x < 64)  bias_c[threadIdx.x] = bc0[threadIdx.x] + bc1[threadIdx.x];
  }
}

// ---------------- K1: adj pass: row/col sums + bf16 copy + transposed bf16 copy
__global__ __launch_bounds__(256) void k1_adj(const float* __restrict__ adj,
    u16* __restrict__ adjbf, u16* __restrict__ adjTbf,
    float* __restrict__ colsum, float* __restrict__ rowsum){
  __shared__ u16 lt[64][72];            // lt[j_local][i_local]
  int b = blockIdx.z;
  int i0 = blockIdx.y << 6, j0 = blockIdx.x << 6;
  int t = threadIdx.x;
  int r = t >> 2, cq = t & 3;
  size_t base = ((size_t)b << 20);
  const float4* s4 = (const float4*)(adj + base + (size_t)(i0 + r)*1024 + j0 + (cq<<4));
  float v[16];
  #pragma unroll
  for (int q = 0; q < 4; q++) {
    float4 f = s4[q];
    v[4*q]=f.x; v[4*q+1]=f.y; v[4*q+2]=f.z; v[4*q+3]=f.w;
  }
  u32 u8[8];
  #pragma unroll
  for (int q = 0; q < 8; q++)
    u8[q] = (u32)f2bf(v[2*q]) | ((u32)f2bf(v[2*q+1]) << 16);
  uint4* d = (uint4*)(adjbf + base + (size_t)(i0 + r)*1024 + j0 + (cq<<4));
  d[0] = make_uint4(u8[0],u8[1],u8[2],u8[3]);
  d[1] = make_uint4(u8[4],u8[5],u8[6],u8[7]);
  float rs = 0.f;
  #pragma unroll
  for (int q = 0; q < 16; q++) rs += v[q];
  rs += __shfl_down(rs, 1, 64);
  rs += __shfl_down(rs, 2, 64);
  if (cq == 0) atomicAdd(&rowsum[b*1024 + i0 + r], rs);
  #pragma unroll
  for (int q = 0; q < 16; q++)
    lt[(cq<<4) + q][r] = (u16)(u8[q>>1] >> ((q&1)*16));
  __syncthreads();
  uint4 q0 = *(const uint4*)&lt[r][(cq<<4)];
  uint4 q1 = *(const uint4*)&lt[r][(cq<<4) + 8];
  uint4* dT = (uint4*)(adjTbf + base + (size_t)(j0 + r)*1024 + i0 + (cq<<4));
  dT[0] = q0; dT[1] = q1;
  u32 w8[8] = {q0.x,q0.y,q0.z,q0.w,q1.x,q1.y,q1.z,q1.w};
  float cs = 0.f;
  #pragma unroll
  for (int q = 0; q < 8; q++)
    cs += bf2f((u16)(w8[q] & 0xFFFFu)) + bf2f((u16)(w8[q] >> 16));
  cs += __shfl_down(cs, 1, 64);
  cs += __shfl_down(cs, 2, 64);
  if (cq == 0) atomicAdd(&colsum[b*1024 + j0 + r], cs);
}

// ---------------- K1c: finalize dinv in place ----
__global__ __launch_bounds__(256) void k1c_dinv(float* __restrict__ colsum,
                                                float* __restrict__ rowsum){
  int i = blockIdx.x*256 + threadIdx.x;   // 16384
  colsum[i] = 1.0f / (colsum[i] + 1.0f);  // becomes d0inv
  rowsum[i] = 1.0f / (rowsum[i] + 1.0f);  // becomes d1inv
}

// ---------------- K1b: stage X = [inp|hx]: XC rows, Xt feature-major, XC2 inp cols
__global__ __launch_bounds__(256) void k1b_x(const float* __restrict__ inp,
    const float* __restrict__ hx, u16* __restrict__ XC,
    u16* __restrict__ Xt, u16* __restrict__ XC2){
  int t = threadIdx.x;
  int row = blockIdx.x*64 + (t>>2);
  int fq = t & 3;
  int b = row >> 10, n = row & 1023;
  const float4* ip = (const float4*)(inp + (size_t)row*64 + fq*16);
  const float4* hp = (const float4*)(hx  + (size_t)row*64 + fq*16);
  float iv[16], hv[16];
  #pragma unroll
  for (int q=0;q<4;q++){
    float4 a = ip[q]; iv[4*q]=a.x; iv[4*q+1]=a.y; iv[4*q+2]=a.z; iv[4*q+3]=a.w;
    float4 c = hp[q]; hv[4*q]=c.x; hv[4*q+1]=c.y; hv[4*q+2]=c.z; hv[4*q+3]=c.w;
  }
  u16 ib[16], hb[16];
  #pragma unroll
  for (int q=0;q<16;q++){ ib[q]=f2bf(iv[q]); hb[q]=f2bf(hv[q]); }
  u32 pi[8], ph[8];
  #pragma unroll
  for (int q=0;q<8;q++){
    pi[q] = (u32)ib[2*q] | ((u32)ib[2*q+1]<<16);
    ph[q] = (u32)hb[2*q] | ((u32)hb[2*q+1]<<16);
  }
  size_t rbase = (size_t)row*384;
  *(uint4*)(XC + rbase + fq*16)          = make_uint4(pi[0],pi[1],pi[2],pi[3]);
  *(uint4*)(XC + rbase + fq*16 + 8)      = make_uint4(pi[4],pi[5],pi[6],pi[7]);
  *(uint4*)(XC + rbase + 64 + fq*16)     = make_uint4(ph[0],ph[1],ph[2],ph[3]);
  *(uint4*)(XC + rbase + 64 + fq*16 + 8) = make_uint4(ph[4],ph[5],ph[6],ph[7]);
  *(uint4*)(XC2 + rbase + fq*16)         = make_uint4(pi[0],pi[1],pi[2],pi[3]);
  *(uint4*)(XC2 + rbase + fq*16 + 8)     = make_uint4(pi[4],pi[5],pi[6],pi[7]);
  u16* Xb = Xt + (size_t)b*131072;
  #pragma unroll
  for (int q=0;q<16;q++){
    Xb[(size_t)(fq*16+q)*1024 + n]      = ib[q];
    Xb[(size_t)(64+fq*16+q)*1024 + n]   = hb[q];
  }
}

// ---------------- K2: Y = dinv * ((adj(+T) @ X) + X) ; LDS-staged MFMA GEMM
// grid 512: mt(16) x b(16) x T(2); block tile 64x128, BK=32, 4 waves each 32x64
__global__ __launch_bounds__(256) void k2_y(const u16* __restrict__ adjbf,
    const u16* __restrict__ adjTbf, const u16* __restrict__ Xt,
    const float* __restrict__ inp, const float* __restrict__ hx,
    const float* __restrict__ d0inv, const float* __restrict__ d1inv,
    u16* __restrict__ XC, u16* __restrict__ XC2){
  __shared__ u16 Al[64*32];    // 4KB, [row][k] rows of 64B
  __shared__ u16 Bl[128*32];   // 8KB, [feat][k]
  int bid = blockIdx.x;
  int mt = bid & 15, b = (bid>>4)&15, T = bid>>8;
  const u16* A = (T ? adjTbf : adjbf) + ((size_t)b<<20) + (size_t)mt*64*1024;
  const float* dinv = (T ? d1inv : d0inv) + b*1024;
  const u16* Xb = Xt + (size_t)b*131072;
  int t = threadIdx.x, w = t>>6, l = t&63, lr = l&15, lg = l>>4;
  int wr = w>>1, wc = w&1;     // wave -> rows wr*32.., cols wc*64..
  // staging source addrs (bytes), advance by kk*2 each step
  const char* Ag  = (const char*)A  + (size_t)(w*16 + (l>>2))*2048 + (l&3)*16;
  const char* Bg0 = (const char*)Xb + (size_t)((w*2  )*16 + (l>>2))*2048 + (l&3)*16;
  const char* Bg1 = (const char*)Xb + (size_t)((w*2+1)*16 + (l>>2))*2048 + (l&3)*16;
  floatx4 acc[2][4] = {};
  for (int kk = 0; kk < 1024; kk += 32){
    if (kk) __syncthreads();              // previous compute done (WAR)
    gl16(Ag  + kk*2, (char*)Al + w*1024);
    gl16(Bg0 + kk*2, (char*)Bl + (w*2  )*1024);
    gl16(Bg1 + kk*2, (char*)Bl + (w*2+1)*1024);
    __syncthreads();                      // vmcnt(0) drained before barrier
    bf16x8 af[2], bfr[4];
    #pragma unroll
    for (int mi = 0; mi < 2; mi++)
      af[mi] = *(const bf16x8*)((const char*)Al + (size_t)(wr*32+mi*16+lr)*64 + lg*16);
    #pragma unroll
    for (int nf = 0; nf < 4; nf++)
      bfr[nf] = *(const bf16x8*)((const char*)Bl + (size_t)(wc*64+nf*16+lr)*64 + lg*16);
    #pragma unroll
    for (int mi = 0; mi < 2; mi++)
      #pragma unroll
      for (int nf = 0; nf < 4; nf++)
        acc[mi][nf] = MFMA16(af[mi], bfr[nf], acc[mi][nf]);
  }
  int outcol = T ? 256 : 128;
  #pragma unroll
  for (int mi = 0; mi < 2; mi++) {
    #pragma unroll
    for (int nf = 0; nf < 4; nf++) {
      #pragma unroll
      for (int rr = 0; rr < 4; rr++) {
        int row = mt*64 + wr*32 + mi*16 + lg*4 + rr;
        int col = wc*64 + nf*16 + lr;
        float xv = (col < 64) ? inp[(size_t)(b*1024+row)*64 + col]
                              : hx [(size_t)(b*1024+row)*64 + (col-64)];
        float v2 = (acc[mi][nf][rr] + xv) * dinv[row];
        u16 bv = f2bf(v2);
        size_t grow = (size_t)(b*1024 + row)*384;
        XC[grow + outcol + col] = bv;
        if (col < 64) XC2[grow + outcol + col] = bv;
      }
    }
  }
}

// ---------------- K3: gates GEMM + sigmoid; emit u and S=r*hx
__global__ __launch_bounds__(256) void k3_gates(const u16* __restrict__ XC,
    const u16* __restrict__ WgT, const float* __restrict__ bias_g,
    const float* __restrict__ hx, u16* __restrict__ XC2,
    u16* __restrict__ St, float* __restrict__ uBuf){
  int w = threadIdx.x >> 6, l = threadIdx.x & 63, lr = l & 15, lg = l >> 4;
  int r0 = blockIdx.x*64 + w*16;
  floatx4 acc[8] = {};
  for (int kk = 0; kk < 384; kk += 32) {
    int ko = kk + lg*8;
    bf16x8 a = ldfrag(XC + (size_t)(r0 + lr)*384 + ko);
    #pragma unroll
    for (int nf = 0; nf < 8; nf++)
      acc[nf] = MFMA16(a, ldfrag(WgT + (size_t)(nf*16+lr)*384 + ko), acc[nf]);
  }
  #pragma unroll
  for (int nf = 0; nf < 8; nf++) {
    #pragma unroll
    for (int rr = 0; rr < 4; rr++) {
      int row = r0 + lg*4 + rr;
      int col = nf*16 + lr;
      float pre = acc[nf][rr] + bias_g[col];
      float s = 1.0f / (1.0f + __expf(-pre));
      if (col < 64) {            // r gate
        float sh = s * hx[(size_t)row*64 + col];
        u16 bv = f2bf(sh);
        XC2[(size_t)row*384 + 64 + col] = bv;
        int gb = row >> 10, n = row & 1023;
        St[(size_t)gb*65536 + (size_t)col*1024 + n] = bv;
      } else {                   // u gate
        uBuf[(size_t)row*64 + (col-64)] = s;
      }
    }
  }
}

// ---------------- K4: Z = dinv * ((adj(+T) @ S) + S) ; LDS-staged MFMA GEMM
// grid 512: mt(16) x b(16) x T(2); block tile 64x64, BK=32, 4 waves each 32x32
__global__ __launch_bounds__(256) void k4_z(const u16* __restrict__ adjbf,
    const u16* __restrict__ adjTbf, const u16* __restrict__ St,
    const float* __restrict__ d0inv, const float* __restrict__ d1inv,
    u16* __restrict__ XC2){
  __shared__ u16 Al[64*32];    // 4KB
  __shared__ u16 Bl[64*32];    // 4KB
  int bid = blockIdx.x;
  int mt = bid & 15, b = (bid>>4)&15, T = bid>>8;
  const u16* A = (T ? adjTbf : adjbf) + ((size_t)b<<20) + (size_t)mt*64*1024;
  const float* dinv = (T ? d1inv : d0inv) + b*1024;
  const u16* Sb = St + (size_t)b*65536;
  int t = threadIdx.x, w = t>>6, l = t&63, lr = l&15, lg = l>>4;
  int wr = w>>1, wc = w&1;     // wave -> rows wr*32.., cols wc*32..
  const char* Ag = (const char*)A  + (size_t)(w*16 + (l>>2))*2048 + (l&3)*16;
  const char* Bg = (const char*)Sb + (size_t)(w*16 + (l>>2))*2048 + (l&3)*16;
  floatx4 acc[2][2] = {};
  for (int kk = 0; kk < 1024; kk += 32){
    if (kk) __syncthreads();
    gl16(Ag + kk*2, (char*)Al + w*1024);
    gl16(Bg + kk*2, (char*)Bl + w*1024);
    __syncthreads();
    bf16x8 af[2], bfr[2];
    #pragma unroll
    for (int mi = 0; mi < 2; mi++)
      af[mi] = *(const bf16x8*)((const char*)Al + (size_t)(wr*32+mi*16+lr)*64 + lg*16);
    #pragma unroll
    for (int nf = 0; nf < 2; nf++)
      bfr[nf] = *(const bf16x8*)((const char*)Bl + (size_t)(wc*32+nf*16+lr)*64 + lg*16);
    #pragma unroll
    for (int mi = 0; mi < 2; mi++)
      #pragma unroll
      for (int nf = 0; nf < 2; nf++)
        acc[mi][nf] = MFMA16(af[mi], bfr[nf], acc[mi][nf]);
  }
  int zcol = T ? 320 : 192;
  #pragma unroll
  for (int mi = 0; mi < 2; mi++) {
    #pragma unroll
    for (int nf = 0; nf < 2; nf++) {
      #pragma unroll
      for (int rr = 0; rr < 4; rr++) {
        int row = mt*64 + wr*32 + mi*16 + lg*4 + rr;
        int col = wc*32 + nf*16 + lr;
        size_t grow = (size_t)(b*1024 + row)*384;
        float sval = bf2f(XC2[grow + 64 + col]);
        float v2 = (acc[mi][nf][rr] + sval) * dinv[row];
        XC2[grow + zcol + col] = f2bf(v2);
      }
    }
  }
}

// ---------------- K5: candidate GEMM + tanh + GRU update -> out
__global__ __launch_bounds__(256) void k5_out(const u16* __restrict__ XC2,
    const u16* __restrict__ WcT, const float* __restrict__ bias_c,
    const float* __restrict__ uBuf, const float* __restrict__ hx,
    float* __restrict__ out){
  int w = threadIdx.x >> 6, l = threadIdx.x & 63, lr = l & 15, lg = l >> 4;
  int r0 = blockIdx.x*64 + w*16;
  floatx4 acc[4] = {};
  for (int kk = 0; kk < 384; kk += 32) {
    int ko = kk + lg*8;
    bf16x8 a = ldfrag(XC2 + (size_t)(r0 + lr)*384 + ko);
    #pragma unroll
    for (int nf = 0; nf < 4; nf++)
      acc[nf] = MFMA16(a, ldfrag(WcT + (size_t)(nf*16+lr)*384 + ko), acc[nf]);
  }
  #pragma unroll
  for (int nf = 0; nf < 4; nf++) {
    #pragma unroll
    for (int rr = 0; rr < 4; rr++) {
      int row = r0 + lg*4 + rr;
      int col = nf*16 + lr;
      float pre = acc[nf][rr] + bias_c[col];
      pre = fminf(fmaxf(pre, -15.f), 15.f);
      float e2 = __expf(2.0f*pre);
      float c = (e2 - 1.0f) / (e2 + 1.0f);
      float u = uBuf[(size_t)row*64 + col];
      float h = hx[(size_t)row*64 + col];
      out[(size_t)row*64 + col] = u*h + (1.0f - u)*c;
    }
  }
}

extern "C" void kernel_launch(void* const* d_in, const int* in_sizes, int n_in,
                              void* d_out, int out_size, void* d_ws, size_t ws_size,
                              hipStream_t stream) {
  (void)in_sizes; (void)n_in; (void)out_size; (void)ws_size;
  const float* inp = (const float*)d_in[0];
  const float* hx  = (const float*)d_in[1];
  const float* adj = (const float*)d_in[2];
  const float* W0  = (const float*)d_in[3];
  const float* b0  = (const float*)d_in[4];
  const float* W1  = (const float*)d_in[5];
  const float* b1  = (const float*)d_in[6];
  const float* Wc0 = (const float*)d_in[7];
  const float* bc0 = (const float*)d_in[8];
  const float* Wc1 = (const float*)d_in[9];
  const float* bc1 = (const float*)d_in[10];
  float* out = (float*)d_out;
  char* ws = (char*)d_ws;

  float* colsum = (float*)(ws + 0);            // -> d0inv after k1c
  float* rowsum = (float*)(ws + 65536);        // -> d1inv after k1c
  u16* adjbf  = (u16*)(ws + 131072);           // 33554432 B
  u16* adjTbf = (u16*)(ws + 33685504);         // 33554432 B
  u16* Xt     = (u16*)(ws + 67239936);         // 4194304 B
  u16* XC     = (u16*)(ws + 71434240);         // 12582912 B
  u16* XC2    = (u16*)(ws + 84017152);         // 12582912 B
  u16* St     = (u16*)(ws + 96600064);         // 2097152 B
  float* uBuf = (float*)(ws + 98697216);       // 4194304 B
  u16* WgT    = (u16*)(ws + 102891520);        // 98304 B
  u16* WcT    = (u16*)(ws + 102989824);        // 49152 B
  float* bias_g = (float*)(ws + 103038976);    // 512 B
  float* bias_c = (float*)(ws + 103039488);    // 256 B

  hipMemsetAsync(ws, 0, 131072, stream);
  hipLaunchKernelGGL(k0_prep, dim3(288), dim3(256), 0, stream,
                     W0, b0, W1, b1, Wc0, bc0, Wc1, bc1, WgT, WcT, bias_g, bias_c);
  hipLaunchKernelGGL(k1_adj, dim3(16,16,16), dim3(256), 0, stream,
                     adj, adjbf, adjTbf, colsum, rowsum);
  hipLaunchKernelGGL(k1c_dinv, dim3(64), dim3(256), 0, stream, colsum, rowsum);
  hipLaunchKernelGGL(k1b_x, dim3(256), dim3(256), 0, stream, inp, hx, XC, Xt, XC2);
  hipLaunchKernelGGL(k2_y, dim3(512), dim3(256), 0, stream,
                     adjbf, adjTbf, Xt, inp, hx, colsum, rowsum, XC, XC2);
  hipLaunchKernelGGL(k3_gates, dim3(256), dim3(256), 0, stream,
                     XC, WgT, bias_g, hx, XC2, St, uBuf);
  hipLaunchKernelGGL(k4_z, dim3(512), dim3(256), 0, stream,
                     adjbf, adjTbf, St, colsum, rowsum, XC2);
  hipLaunchKernelGGL(k5_out, dim3(256), dim3(256), 0, stream,
                     XC2, WcT, bias_c, uBuf, hx, out);
}